// Round 1
// baseline (86.809 us; speedup 1.0000x reference)
//
#include <hip/hip_runtime.h>

// Problem constants (from reference)
#define B 4
#define C 16
#define NF 10000
#define LL 100000

constexpr int BC = B * C;                       // 64
constexpr int CHUNKS = 32;                      // l-chunks per (b,c)
constexpr int CHUNK = (LL + CHUNKS - 1) / CHUNKS; // 3125
constexpr int BLOCK = 256;

__global__ __launch_bounds__(BLOCK) void mse_main(
    const float* __restrict__ i_f, const float* __restrict__ i_s,
    const float* __restrict__ t_f, const float* __restrict__ t_s,
    const int*  __restrict__ xi,  const float* __restrict__ ks,
    double* __restrict__ acc)
{
    const int bc    = blockIdx.x / CHUNKS;
    const int chunk = blockIdx.x % CHUNKS;
    const int l0 = chunk * CHUNK;
    const int l1 = (l0 + CHUNK < LL) ? (l0 + CHUNK) : LL;

    const float2* __restrict__ isv = (const float2*)i_s + (size_t)bc * LL;
    const float2* __restrict__ tsv = (const float2*)t_s + (size_t)bc * LL;
    const float2* __restrict__ ifv = (const float2*)i_f + (size_t)bc * NF;
    const float2* __restrict__ tfv = (const float2*)t_f + (size_t)bc * NF;
    const int2*   __restrict__ xiv = (const int2*)xi;
    const float2* __restrict__ ksv = (const float2*)ks;

    float sum = 0.f;
    for (int l = l0 + (int)threadIdx.x; l < l1; l += BLOCK) {
        float2 si = isv[l];
        float2 st = tsv[l];
        float gr = si.x - st.x;
        float gi = si.y - st.y;

        float2 k = ksv[l];
        // Both correction terms vanish unless BOTH masks are false:
        // term1 = f0*conj(tf1): f0 zeroed by (k0>0), tf1 zeroed by (k1>0)
        // term2 = tf0*conj(f1): tf0 zeroed by (k0>0), f1 zeroed by (k1>0)
        if (!(k.x > 0.f) && !(k.y > 0.f)) {
            int2 idx = xiv[l];
            float2 tf0 = tfv[idx.x];
            float2 if0 = ifv[idx.x];
            float2 tf1 = tfv[idx.y];
            float2 if1 = ifv[idx.y];
            float f0r = if0.x - tf0.x, f0i = if0.y - tf0.y;
            float f1r = if1.x - tf1.x, f1i = if1.y - tf1.y;
            // cmul_conj(a,b) = (ar*br + ai*bi, ai*br - ar*bi)
            gr -= f0r * tf1.x + f0i * tf1.y;
            gi -= f0i * tf1.x - f0r * tf1.y;
            gr -= tf0.x * f1r + tf0.y * f1i;
            gi -= tf0.y * f1r - tf0.x * f1i;
        }
        sum += gr * gr + gi * gi;
    }

    // wave-level reduce (64 lanes)
    #pragma unroll
    for (int off = 32; off; off >>= 1)
        sum += __shfl_down(sum, off, 64);

    __shared__ float ws[BLOCK / 64];
    const int lane = threadIdx.x & 63;
    const int wid  = threadIdx.x >> 6;
    if (lane == 0) ws[wid] = sum;
    __syncthreads();
    if (threadIdx.x == 0) {
        float t = 0.f;
        #pragma unroll
        for (int i = 0; i < BLOCK / 64; ++i) t += ws[i];
        atomicAdd(acc, (double)t);
    }
}

__global__ void mse_finalize(const double* __restrict__ acc, float* __restrict__ out)
{
    out[0] = (float)(acc[0] / (double)((size_t)B * C * LL));
}

extern "C" void kernel_launch(void* const* d_in, const int* in_sizes, int n_in,
                              void* d_out, int out_size, void* d_ws, size_t ws_size,
                              hipStream_t stream)
{
    const float* i_f = (const float*)d_in[0];
    const float* i_s = (const float*)d_in[1];
    const float* t_f = (const float*)d_in[2];
    const float* t_s = (const float*)d_in[3];
    const int*   xi  = (const int*)d_in[4];
    const float* ks  = (const float*)d_in[5];
    float* out = (float*)d_out;
    double* acc = (double*)d_ws;

    hipMemsetAsync(acc, 0, sizeof(double), stream);
    mse_main<<<BC * CHUNKS, BLOCK, 0, stream>>>(i_f, i_s, t_f, t_s, xi, ks, acc);
    mse_finalize<<<1, 1, 0, stream>>>(acc, out);
}

// Round 3
// 62.580 us; speedup vs baseline: 1.3872x; 1.3872x over previous
//
#include <hip/hip_runtime.h>

// Problem constants (from reference)
#define NB 4
#define NC 16
#define NF 10000
#define LL 100000

typedef float f32x2 __attribute__((ext_vector_type(2)));

constexpr int BC = NB * NC;        // 64
constexpr int BLOCK = 256;
constexpr int TL = 64;             // l's per main block
constexpr int NBLK = (LL + TL - 1) / TL;   // 1563
constexpr int CSTR = 65;           // corr row stride in float2 (pad)

// workspace layout
constexpr size_t WS_ACC   = 0;                       // double
constexpr size_t WS_FGAPT = 256;                     // NF*64 float2 = 5,120,000 B
constexpr size_t WS_TFT   = 256 + (size_t)NF * 64 * 8;
constexpr size_t WS_NEED  = WS_TFT + (size_t)NF * 64 * 8;

// ---------- prep: LDS-tiled transpose into [nf][bc] rows ----------
__global__ __launch_bounds__(256) void transpose_prep(
    const float2* __restrict__ i_f, const float2* __restrict__ t_f,
    float2* __restrict__ fgap_t, float2* __restrict__ tft)
{
    __shared__ float2 tg[64][65];
    __shared__ float2 tt[64][65];
    const int nf0  = blockIdx.x * 64;
    const int nrem = min(64, NF - nf0);
    const int lane = threadIdx.x & 63;
    const int q    = threadIdx.x >> 6;
    if (lane < nrem) {
        for (int bc = q; bc < BC; bc += 4) {
            float2 iv = i_f[(size_t)bc * NF + nf0 + lane];
            float2 tv = t_f[(size_t)bc * NF + nf0 + lane];
            tg[bc][lane] = make_float2(iv.x - tv.x, iv.y - tv.y);
            tt[bc][lane] = tv;
        }
    }
    __syncthreads();
    for (int j = q; j < nrem; j += 4) {
        fgap_t[(size_t)(nf0 + j) * BC + lane] = tg[lane][j];
        tft  [(size_t)(nf0 + j) * BC + lane] = tt[lane][j];
    }
}

// ---------- main: compacted coalesced gather + coalesced streams ----------
__global__ __launch_bounds__(BLOCK) void mse_main2(
    const float* __restrict__ i_s, const float* __restrict__ t_s,
    const int2*  __restrict__ xi,  const float2* __restrict__ ks,
    const float2* __restrict__ fgap_t, const float2* __restrict__ tft,
    double* __restrict__ acc)
{
    __shared__ float2 corr[TL * CSTR];
    __shared__ int2   xi_list[TL];
    __shared__ int    pos[TL];
    __shared__ int    cnt;
    __shared__ float  wsum[BLOCK / 64];

    const int l0   = blockIdx.x * TL;
    const int tlb  = min(TL, LL - l0);
    const int lane = threadIdx.x & 63;
    const int wid  = threadIdx.x >> 6;
    const int tid  = threadIdx.x;

    if (tid == 0) cnt = 0;
    if (tid < TL) pos[tid] = -1;
    __syncthreads();

    // classify + compact active l's (both correction masks false)
    if (tid < tlb) {
        float2 k = ks[l0 + tid];
        if (!(k.x > 0.f) && !(k.y > 0.f)) {
            int slot = atomicAdd(&cnt, 1);
            pos[tid] = slot;
            xi_list[slot] = xi[l0 + tid];
        }
    }
    __syncthreads();

    // per active slot: one wave gathers 4 coalesced 512B rows, computes corr[bc]
    const int nact = cnt;
    for (int a = wid; a < nact; a += BLOCK / 64) {
        int2 idx = xi_list[a];
        float2 f0  = fgap_t[(size_t)idx.x * BC + lane];
        float2 tf1 = tft  [(size_t)idx.y * BC + lane];
        float2 tf0 = tft  [(size_t)idx.x * BC + lane];
        float2 f1  = fgap_t[(size_t)idx.y * BC + lane];
        // cmul_conj(a,b) = (ar*br + ai*bi, ai*br - ar*bi)
        float cr = f0.x * tf1.x + f0.y * tf1.y + tf0.x * f1.x + tf0.y * f1.y;
        float ci = f0.y * tf1.x - f0.x * tf1.y + tf0.y * f1.x - tf0.x * f1.y;
        corr[a * CSTR + lane] = make_float2(cr, ci);
    }
    __syncthreads();

    // streams: lane <-> l (coalesced 512B), loop over bc per wave
    float sum = 0.f;
    if (lane < tlb) {
        const int l = l0 + lane;
        const int myslot = pos[lane];
        for (int bc = wid; bc < BC; bc += BLOCK / 64) {
            const f32x2* ip = (const f32x2*)(i_s + 2 * ((size_t)bc * LL + l));
            const f32x2* tp = (const f32x2*)(t_s + 2 * ((size_t)bc * LL + l));
            f32x2 si = __builtin_nontemporal_load(ip);
            f32x2 st = __builtin_nontemporal_load(tp);
            float gr = si.x - st.x;
            float gi = si.y - st.y;
            if (myslot >= 0) {
                float2 cc = corr[myslot * CSTR + bc];
                gr -= cc.x;
                gi -= cc.y;
            }
            sum += gr * gr + gi * gi;
        }
    }

    #pragma unroll
    for (int off = 32; off; off >>= 1) sum += __shfl_down(sum, off, 64);
    if (lane == 0) wsum[wid] = sum;
    __syncthreads();
    if (tid == 0) {
        float t = wsum[0] + wsum[1] + wsum[2] + wsum[3];
        atomicAdd(acc, (double)t);
    }
}

// ---------- fallback (round-1 kernel) if workspace too small ----------
constexpr int FCHUNKS = 32;
constexpr int FCHUNK  = (LL + FCHUNKS - 1) / FCHUNKS;

__global__ __launch_bounds__(BLOCK) void mse_fallback(
    const float* __restrict__ i_f, const float* __restrict__ i_s,
    const float* __restrict__ t_f, const float* __restrict__ t_s,
    const int*  __restrict__ xi,  const float* __restrict__ ks,
    double* __restrict__ acc)
{
    const int bc    = blockIdx.x / FCHUNKS;
    const int chunk = blockIdx.x % FCHUNKS;
    const int l0 = chunk * FCHUNK;
    const int l1 = (l0 + FCHUNK < LL) ? (l0 + FCHUNK) : LL;

    const float2* isv = (const float2*)i_s + (size_t)bc * LL;
    const float2* tsv = (const float2*)t_s + (size_t)bc * LL;
    const float2* ifv = (const float2*)i_f + (size_t)bc * NF;
    const float2* tfv = (const float2*)t_f + (size_t)bc * NF;
    const int2*   xiv = (const int2*)xi;
    const float2* ksv = (const float2*)ks;

    float sum = 0.f;
    for (int l = l0 + (int)threadIdx.x; l < l1; l += BLOCK) {
        float2 si = isv[l], st = tsv[l];
        float gr = si.x - st.x, gi = si.y - st.y;
        float2 k = ksv[l];
        if (!(k.x > 0.f) && !(k.y > 0.f)) {
            int2 idx = xiv[l];
            float2 tf0 = tfv[idx.x], if0 = ifv[idx.x];
            float2 tf1 = tfv[idx.y], if1 = ifv[idx.y];
            float f0r = if0.x - tf0.x, f0i = if0.y - tf0.y;
            float f1r = if1.x - tf1.x, f1i = if1.y - tf1.y;
            gr -= f0r * tf1.x + f0i * tf1.y;
            gi -= f0i * tf1.x - f0r * tf1.y;
            gr -= tf0.x * f1r + tf0.y * f1i;
            gi -= tf0.y * f1r - tf0.x * f1i;
        }
        sum += gr * gr + gi * gi;
    }
    #pragma unroll
    for (int off = 32; off; off >>= 1) sum += __shfl_down(sum, off, 64);
    __shared__ float ws[BLOCK / 64];
    const int lane = threadIdx.x & 63, wwid = threadIdx.x >> 6;
    if (lane == 0) ws[wwid] = sum;
    __syncthreads();
    if (threadIdx.x == 0) {
        float t = 0.f;
        #pragma unroll
        for (int i = 0; i < BLOCK / 64; ++i) t += ws[i];
        atomicAdd(acc, (double)t);
    }
}

__global__ void mse_finalize(const double* __restrict__ acc, float* __restrict__ out)
{
    out[0] = (float)(acc[0] / (double)((size_t)BC * LL));
}

extern "C" void kernel_launch(void* const* d_in, const int* in_sizes, int n_in,
                              void* d_out, int out_size, void* d_ws, size_t ws_size,
                              hipStream_t stream)
{
    const float* i_f = (const float*)d_in[0];
    const float* i_s = (const float*)d_in[1];
    const float* t_f = (const float*)d_in[2];
    const float* t_s = (const float*)d_in[3];
    const int*   xi  = (const int*)d_in[4];
    const float* ks  = (const float*)d_in[5];
    float* out = (float*)d_out;

    char* ws = (char*)d_ws;
    double* acc = (double*)(ws + WS_ACC);
    (void)hipMemsetAsync(acc, 0, sizeof(double), stream);

    if (ws_size >= WS_NEED) {
        float2* fgap_t = (float2*)(ws + WS_FGAPT);
        float2* tft    = (float2*)(ws + WS_TFT);
        transpose_prep<<<(NF + 63) / 64, 256, 0, stream>>>(
            (const float2*)i_f, (const float2*)t_f, fgap_t, tft);
        mse_main2<<<NBLK, BLOCK, 0, stream>>>(
            i_s, t_s, (const int2*)xi, (const float2*)ks, fgap_t, tft, acc);
    } else {
        mse_fallback<<<BC * FCHUNKS, BLOCK, 0, stream>>>(
            i_f, i_s, t_f, t_s, xi, ks, acc);
    }
    mse_finalize<<<1, 1, 0, stream>>>(acc, out);
}